// Round 2
// baseline (208.457 us; speedup 1.0000x reference)
//
#include <hip/hip_runtime.h>
#include <hip/hip_fp16.h>

// GCN 2-layer, pull-based CSR gather, fp16 dense intermediates.
// R16 = R15 + latency-chain attack on the gathers:
//  (a) deg_k pre-pass (800k global atomics) -> gemm1 epilogue pre-scales
//      h1 rows by rsqrt(1+deg): gather1 loses the per-edge dinv[src] weight
//      (no dw bpermute, no uncoalesced dinv gather) - same pure-sum form
//      that gather2 already uses.
//  (b) half-wave-per-node in both gathers: 2 independent nodes per wave
//      (128 dims = 32 lanes x f16x4 / 64 dims = 32 lanes x half2), no
//      cross-half reduce, halves the per-wave serial node chain.
//  (c) 4-edge unroll per half -> 4 independent row loads in flight.
// Edge preprocessing (bucket counting sort) unchanged. N <= 65536.

typedef _Float16 half_t;
typedef _Float16 half2_t __attribute__((ext_vector_type(2)));
typedef _Float16 f16x4 __attribute__((ext_vector_type(4)));
typedef _Float16 f16x8 __attribute__((ext_vector_type(8)));
typedef float f32x4 __attribute__((ext_vector_type(4)));

#define BKT_CAP 8192   // per-bucket ebuf capacity (expected load 4096, sigma 64)

// inclusive block scan over 256 threads (4 waves); caller provides 4-int LDS
__device__ __forceinline__ int incl_scan256(int v, volatile int* wsum) {
    int t = threadIdx.x, lane = t & 63, w = t >> 6;
#pragma unroll
    for (int off = 1; off < 64; off <<= 1) {
        int u = __shfl_up(v, off);
        if (lane >= off) v += u;
    }
    if (lane == 63) wsum[w] = v;
    __syncthreads();
    int add = 0;
#pragma unroll
    for (int i = 0; i < 3; ++i)
        if (i < w) add += wsum[i];
    return v + add;
}

// ---------------- deg_k: in-degree count (for gemm1 epilogue pre-scale) ----

__launch_bounds__(256)
__global__ void deg_k(const int* __restrict__ edst, int* __restrict__ deg, int E) {
    int base = blockIdx.x * 2048 + threadIdx.x;
#pragma unroll
    for (int j = 0; j < 8; ++j) {
        int i = base + j * 256;
        if (i < E) atomicAdd(&deg[edst[i]], 1);
    }
}

// ---------------- gemm1: 128x128 tile via f16 MFMA ----------------
// MFMA 16x16x32 layouts (gfx950, HW-verified):
//   A-frag: lane holds A[m=lane&15][k=(lane>>4)*8+j]
//   B-frag: lane holds B[k=(lane>>4)*8+j][n=lane&15]
//   C/D   : col=lane&15, row=(lane>>4)*4+reg
// Epilogue pre-scales row by rsqrt(1+deg[row]) (dinv), so the gather is a
// pure unweighted sum.

__device__ __forceinline__ void gemm1_mfma(const float* __restrict__ x,
                                           const float* __restrict__ W,
                                           const int* __restrict__ deg,
                                           half_t* __restrict__ C, int M, int r0) {
    __shared__ _Float16 Wt[128][136];          // [n][k], rows 272B (b128-aligned)
    __shared__ _Float16 Xs[128][40];           // [m][k-chunk], rows 80B
    const int t = threadIdx.x;

    // stage W^T fp16: coalesced reads along n, b64 writes along k
    {
        const int n = t & 127;
#pragma unroll
        for (int kb = (t >> 7) * 4; kb < 128; kb += 8) {
            f16x4 hv;
            hv[0] = (_Float16)W[(size_t)(kb + 0) * 128 + n];
            hv[1] = (_Float16)W[(size_t)(kb + 1) * 128 + n];
            hv[2] = (_Float16)W[(size_t)(kb + 2) * 128 + n];
            hv[3] = (_Float16)W[(size_t)(kb + 3) * 128 + n];
            *(f16x4*)&Wt[n][kb] = hv;
        }
    }

    const int w = t >> 6, lane = t & 63;
    const int m = lane & 15, q = lane >> 4;

    // Xs staging coords: 16 floats (one row-half-chunk) per thread per kc
    const int sr = t >> 1;               // 0..127 tile row
    const int sk = (t & 1) * 16;         // 0 or 16 within 32-k chunk
    const int srow = (r0 + sr < M) ? (r0 + sr) : (M - 1);

    f32x4 acc[2][8];
#pragma unroll
    for (int rt = 0; rt < 2; ++rt)
#pragma unroll
        for (int ct = 0; ct < 8; ++ct)
#pragma unroll
            for (int r = 0; r < 4; ++r) acc[rt][ct][r] = 0.f;

#pragma unroll
    for (int kc = 0; kc < 4; ++kc) {
        // coalesced global loads issued before the barrier (overlap prev MFMAs)
        const float* xp = &x[(size_t)srow * 128 + kc * 32 + sk];
        float4 v0 = *(const float4*)xp;
        float4 v1 = *(const float4*)(xp + 4);
        float4 v2 = *(const float4*)(xp + 8);
        float4 v3 = *(const float4*)(xp + 12);
        __syncthreads();                 // prev iter's Xs reads done (&& Wt staged)
        f16x8 s0, s1;
        s0[0] = (_Float16)v0.x; s0[1] = (_Float16)v0.y;
        s0[2] = (_Float16)v0.z; s0[3] = (_Float16)v0.w;
        s0[4] = (_Float16)v1.x; s0[5] = (_Float16)v1.y;
        s0[6] = (_Float16)v1.z; s0[7] = (_Float16)v1.w;
        s1[0] = (_Float16)v2.x; s1[1] = (_Float16)v2.y;
        s1[2] = (_Float16)v2.z; s1[3] = (_Float16)v2.w;
        s1[4] = (_Float16)v3.x; s1[5] = (_Float16)v3.y;
        s1[6] = (_Float16)v3.z; s1[7] = (_Float16)v3.w;
        *(f16x8*)&Xs[sr][sk] = s0;
        *(f16x8*)&Xs[sr][sk + 8] = s1;
        __syncthreads();

        const int k0 = q * 8;
        f16x8 a0 = *(const f16x8*)&Xs[(w * 2 + 0) * 16 + m][k0];
        f16x8 a1 = *(const f16x8*)&Xs[(w * 2 + 1) * 16 + m][k0];
        const int kw = kc * 32 + k0;
#pragma unroll
        for (int ct = 0; ct < 8; ++ct) {
            f16x8 b = *(const f16x8*)&Wt[ct * 16 + m][kw];
            acc[0][ct] = __builtin_amdgcn_mfma_f32_16x16x32_f16(a0, b, acc[0][ct], 0, 0, 0);
            acc[1][ct] = __builtin_amdgcn_mfma_f32_16x16x32_f16(a1, b, acc[1][ct], 0, 0, 0);
        }
    }

#pragma unroll
    for (int rt = 0; rt < 2; ++rt)
#pragma unroll
        for (int r = 0; r < 4; ++r) {
            int row = r0 + (w * 2 + rt) * 16 + q * 4 + r;
            if (row < M) {
                float s = rsqrtf(1.0f + (float)deg[row]);   // dinv[row]
#pragma unroll
                for (int ct = 0; ct < 8; ++ct)
                    C[(size_t)row * 128 + ct * 16 + m] = (half_t)(acc[rt][ct][r] * s);
            }
        }
}

// ---------------- k1: gemm1 blocks, then pass-A binning blocks --------------

__launch_bounds__(256)
__global__ void gemm_binA_k(const float* __restrict__ A, const float* __restrict__ W,
                            const int* __restrict__ deg,
                            half_t* __restrict__ C, int M, int Gg1,
                            const int* __restrict__ esrc, const int* __restrict__ edst,
                            int* __restrict__ bucket_cnt, unsigned int* __restrict__ ebuf,
                            int E) {
    int b = blockIdx.x;
    if (b < Gg1) {
        gemm1_mfma(A, W, deg, C, M, b * 128);
        return;
    }
    __shared__ int cntA[256];
    __shared__ int curA[256];
    __shared__ int deltaA[256];
    __shared__ int wsumA[4];

    const int t = threadIdx.x;
    const int base = (b - Gg1) * 4096;
    int ls[16], ld[16];

    cntA[t] = 0;
    __syncthreads();
#pragma unroll
    for (int j = 0; j < 16; ++j) {
        int idx = base + j * 256 + t;
        if (idx < E) {
            ls[j] = esrc[idx];
            ld[j] = edst[idx];
            atomicAdd(&cntA[ld[j] >> 8], 1);
        } else {
            ls[j] = -1;
            ld[j] = 0;
        }
    }
    __syncthreads();

    int c = cntA[t];
    int incl = incl_scan256(c, wsumA);      // contains a __syncthreads
    int excl = incl - c;
    int gbase = atomicAdd(&bucket_cnt[t], c);       // offset within bucket segment
    deltaA[t] = t * BKT_CAP + gbase - excl;         // absolute = seg base + offset
    curA[t] = excl;
    __syncthreads();

#pragma unroll
    for (int j = 0; j < 16; ++j) {
        if (ls[j] >= 0) {
            int bkt = ld[j] >> 8;
            int p = atomicAdd(&curA[bkt], 1);
            ebuf[deltaA[bkt] + p] = ((unsigned int)ls[j] << 8) | ((unsigned int)ld[j] & 255u);
        }
    }
}

// ---------------- k2 (pass B): per-bucket counting sort -> rs/dinv/ssrc -----

__launch_bounds__(256)
__global__ void binB_k(const int* __restrict__ bucket_cnt,
                       const unsigned int* __restrict__ ebuf,
                       unsigned short* __restrict__ ssrc,
                       int* __restrict__ rs, float* __restrict__ dinv,
                       int N, int NB) {
    __shared__ int cnt[256];
    __shared__ int pre[256];
    __shared__ int wsum1[4];
    __shared__ int wsum2[4];

    const int t = threadIdx.x;
    const int b = blockIdx.x;

    int v = (t < NB) ? bucket_cnt[t] : 0;
    int inclb = incl_scan256(v, wsum1);
    pre[t] = inclb;
    __syncthreads();
    const int gb = (b > 0) ? pre[b - 1] : 0;
    const int sz = pre[b] - gb;
    const unsigned int* seg = ebuf + (size_t)b * BKT_CAP;

    cnt[t] = 0;
    __syncthreads();
    for (int i = t; i < sz; i += 256) {
        unsigned int pk = seg[i];
        atomicAdd(&cnt[pk & 255u], 1);
    }
    __syncthreads();

    int c = cnt[t];
    int incl = incl_scan256(c, wsum2);
    int excl = incl - c;
    int node = b * 256 + t;
    if (node < N) {
        rs[node] = gb + excl;
        dinv[node] = rsqrtf(1.0f + (float)c);
    }
    __syncthreads();
    cnt[t] = excl;
    __syncthreads();

    for (int i = t; i < sz; i += 256) {
        unsigned int pk = seg[i];
        int p = atomicAdd(&cnt[pk & 255u], 1);
        ssrc[gb + p] = (unsigned short)(pk >> 8);
    }
}

// ---------------- g1mm: fused gather1 (half-wave/node, unweighted) + gemm2 --
// hs rows are pre-scaled by dinv (gemm1 epilogue), so the aggregate is a
// pure sum: out_row = relu(dv * (sum_in hs[s] + hs[node]) + b1).
// Per block: 16 nodes; each wave owns 4 (2 serial pairs, one node per
// 32-lane half). Rows land in LDS g1s, then M=16 MFMA with W2^T; epilogue
// scales by dinv (pre-scaling hs2 for gather2).

__launch_bounds__(256)
__global__ void g1mm_k(const half_t* __restrict__ hs,
                       const unsigned short* __restrict__ ssrc,
                       const int* __restrict__ rs,
                       const float* __restrict__ dinv,
                       const float* __restrict__ b1,
                       const float* __restrict__ W2,
                       half_t* __restrict__ o, int N, int E) {
    __shared__ _Float16 Wt[64][136];           // [n][k], W2^T fp16
    __shared__ _Float16 g1s[16][136];          // gathered+activated rows
    const int t = threadIdx.x;

    // stage W2^T fp16: coalesced reads along n, b64 writes along k
    {
        const int n = t & 63;
#pragma unroll
        for (int kb = (t >> 6) * 4; kb < 128; kb += 16) {
            f16x4 hv;
            hv[0] = (_Float16)W2[(size_t)(kb + 0) * 64 + n];
            hv[1] = (_Float16)W2[(size_t)(kb + 1) * 64 + n];
            hv[2] = (_Float16)W2[(size_t)(kb + 2) * 64 + n];
            hv[3] = (_Float16)W2[(size_t)(kb + 3) * 64 + n];
            *(f16x4*)&Wt[n][kb] = hv;
        }
    }

    const int w = t >> 6, lane = t & 63;
    const int hl = lane >> 5, l5 = lane & 31;
    const int nb = blockIdx.x * 16;
    const half_t* hp = hs + 4 * l5;            // dims 4*l5 .. 4*l5+3
    const int sl = hl * 32;                    // shfl base for this half

#pragma unroll 1
    for (int i = 0; i < 2; ++i) {
        int node = nb + w * 4 + i * 2 + hl;    // this half's node
        int vnode = (node < N) ? node : (N - 1);
        int start = rs[vnode];
        int end = (vnode + 1 < N) ? rs[vnode + 1] : E;
        float dv = dinv[vnode];

        f16x4 sv = *(const f16x4*)&hp[(size_t)vnode * 128];   // self (pre-scaled)
        float acc[4];
#pragma unroll
        for (int j = 0; j < 4; ++j) acc[j] = (float)sv[j];

        for (int base = start; base < end; base += 32) {
            int n = end - base;
            if (n > 32) n = 32;
            int gi = (base + l5 < end) ? (base + l5) : base;
            int idx = (int)ssrc[gi];
            int e = 0;
            for (; e + 4 <= n; e += 4) {       // 4 edges/iter per half
                int s0 = __shfl(idx, sl + e + 0);
                int s1 = __shfl(idx, sl + e + 1);
                int s2 = __shfl(idx, sl + e + 2);
                int s3 = __shfl(idx, sl + e + 3);
                f16x4 x0 = *(const f16x4*)&hp[(size_t)s0 * 128];
                f16x4 x1 = *(const f16x4*)&hp[(size_t)s1 * 128];
                f16x4 x2 = *(const f16x4*)&hp[(size_t)s2 * 128];
                f16x4 x3 = *(const f16x4*)&hp[(size_t)s3 * 128];
#pragma unroll
                for (int j = 0; j < 4; ++j) acc[j] += (float)x0[j];
#pragma unroll
                for (int j = 0; j < 4; ++j) acc[j] += (float)x1[j];
#pragma unroll
                for (int j = 0; j < 4; ++j) acc[j] += (float)x2[j];
#pragma unroll
                for (int j = 0; j < 4; ++j) acc[j] += (float)x3[j];
            }
            for (; e < n; ++e) {
                int s0 = __shfl(idx, sl + e);
                f16x4 x0 = *(const f16x4*)&hp[(size_t)s0 * 128];
#pragma unroll
                for (int j = 0; j < 4; ++j) acc[j] += (float)x0[j];
            }
        }

        // epilogue: relu(acc*dv + b1) -> LDS row (each half owns a full row)
        float4 bb = *(const float4*)&b1[4 * l5];
        f16x4 hv;
        hv[0] = (half_t)fmaxf(acc[0] * dv + bb.x, 0.f);
        hv[1] = (half_t)fmaxf(acc[1] * dv + bb.y, 0.f);
        hv[2] = (half_t)fmaxf(acc[2] * dv + bb.z, 0.f);
        hv[3] = (half_t)fmaxf(acc[3] * dv + bb.w, 0.f);
        *(f16x4*)&g1s[w * 4 + i * 2 + hl][4 * l5] = hv;
    }
    __syncthreads();

    // M=16 x N=64 x K=128 MFMA; wave w owns output cols w*16..w*16+15
    const int m = lane & 15, q = lane >> 4;
    f32x4 acc2;
#pragma unroll
    for (int r = 0; r < 4; ++r) acc2[r] = 0.f;
#pragma unroll
    for (int kc = 0; kc < 4; ++kc) {
        const int k0 = kc * 32 + q * 8;
        f16x8 a = *(const f16x8*)&g1s[m][k0];
        f16x8 b = *(const f16x8*)&Wt[w * 16 + m][k0];
        acc2 = __builtin_amdgcn_mfma_f32_16x16x32_f16(a, b, acc2, 0, 0, 0);
    }
#pragma unroll
    for (int r = 0; r < 4; ++r) {
        int row = nb + q * 4 + r;
        if (row < N) {
            float s = dinv[row];
            o[(size_t)row * 64 + w * 16 + m] = (half_t)(acc2[r] * s);
        }
    }
}

// ---------------- gather2: 64-dim, half-wave per node, fp32 out -------------

__global__ void gather2_k(const half_t* __restrict__ hs,
                          const unsigned short* __restrict__ ssrc,
                          const int* __restrict__ rs,
                          const float* __restrict__ dinv,
                          const float* __restrict__ bias,
                          float* __restrict__ o, int N, int E) {
    int wid = (int)((blockIdx.x * blockDim.x + threadIdx.x) >> 6);
    int lane = threadIdx.x & 63;
    const int hl = lane >> 5, l5 = lane & 31;
    int rnode = wid * 2 + hl;                  // this half's node
    int node = (rnode < N) ? rnode : (N - 1);

    int start = rs[node];
    int end = (node + 1 < N) ? rs[node + 1] : E;
    float dv = dinv[node];
    const int sl = hl * 32;

    const half_t* hp = hs + 2 * l5;            // dims 2*l5, 2*l5+1
    half2_t sv = *(const half2_t*)&hp[(size_t)node * 64];
    float ax = (float)sv.x;                    // self (hs pre-scaled by dinv)
    float ay = (float)sv.y;

    for (int base = start; base < end; base += 32) {
        int n = end - base;
        if (n > 32) n = 32;
        int gi = (base + l5 < end) ? (base + l5) : base;
        int idx = (int)ssrc[gi];
        int e = 0;
        for (; e + 4 <= n; e += 4) {           // 4 edges/iter per half
            int s0 = __shfl(idx, sl + e + 0);
            int s1 = __shfl(idx, sl + e + 1);
            int s2 = __shfl(idx, sl + e + 2);
            int s3 = __shfl(idx, sl + e + 3);
            half2_t a0 = *(const half2_t*)&hp[(size_t)s0 * 64];
            half2_t a1 = *(const half2_t*)&hp[(size_t)s1 * 64];
            half2_t a2 = *(const half2_t*)&hp[(size_t)s2 * 64];
            half2_t a3 = *(const half2_t*)&hp[(size_t)s3 * 64];
            ax += (float)a0.x; ay += (float)a0.y;
            ax += (float)a1.x; ay += (float)a1.y;
            ax += (float)a2.x; ay += (float)a2.y;
            ax += (float)a3.x; ay += (float)a3.y;
        }
        for (; e < n; ++e) {
            int s0 = __shfl(idx, sl + e);
            half2_t a0 = *(const half2_t*)&hp[(size_t)s0 * 64];
            ax += (float)a0.x; ay += (float)a0.y;
        }
    }
    if (rnode < N) {
        float2 bb = *(const float2*)&bias[2 * l5];
        float2 st;
        st.x = ax * dv + bb.x;
        st.y = ay * dv + bb.y;
        *(float2*)&o[(size_t)rnode * 64 + 2 * l5] = st;
    }
}

// ---------------- launcher ----------------

extern "C" void kernel_launch(void* const* d_in, const int* in_sizes, int n_in,
                              void* d_out, int out_size, void* d_ws, size_t ws_size,
                              hipStream_t stream) {
    const float* x  = (const float*)d_in[0];
    const int*   ei = (const int*)d_in[1];
    const float* W1 = (const float*)d_in[2];
    const float* b1 = (const float*)d_in[3];
    const float* W2 = (const float*)d_in[4];
    const float* b2 = (const float*)d_in[5];
    float* out = (float*)d_out;

    const int N = in_sizes[0] / 128;
    const int E = in_sizes[1] / 2;
    const int* esrc = ei;
    const int* edst = ei + E;

    const int NB  = (N + 255) / 256;          // buckets (<=256 requires N<=65536)
    const int Gg1 = (N + 127) / 128;
    const int GA  = (E + 4095) / 4096;

    // workspace layout
    int* bucket_cnt = (int*)d_ws;                             // 256
    int* deg = bucket_cnt + 256;                              // N (in-degree)
    unsigned int* ebuf = (unsigned int*)(deg + N);            // NB*BKT_CAP packed edges
    unsigned short* ssrc = (unsigned short*)(ebuf + (size_t)NB * BKT_CAP); // E uint16
    int* rs = (int*)(ssrc + ((E + 1) & ~1));                  // N
    float* dinv = (float*)(rs + N);                           // N
    half_t* hs1 = (half_t*)(dinv + N);                        // N*128 fp16 (pre-scaled)
    half_t* hs2 = hs1 + (size_t)N * 128;                      // N*64 fp16 (pre-scaled)

    hipMemsetAsync(bucket_cnt, 0, (256 + N) * 4, stream);

    // k0: in-degree count (needed by gemm1's pre-scale epilogue)
    hipLaunchKernelGGL(deg_k, dim3((E + 2047) / 2048), dim3(256), 0, stream,
                       edst, deg, E);
    // k1: gemm1 (dinv-pre-scaled fp16 h1) ∪ pass-A edge binning
    hipLaunchKernelGGL(gemm_binA_k, dim3(Gg1 + GA), dim3(256), 0, stream,
                       x, W1, deg, hs1, N, Gg1, esrc, edst, bucket_cnt, ebuf, E);
    // k2: per-bucket counting sort -> rs, dinv, ssrc
    hipLaunchKernelGGL(binB_k, dim3(NB), dim3(256), 0, stream,
                       bucket_cnt, ebuf, ssrc, rs, dinv, N, NB);
    // fused layer-1 aggregate + layer-2 linear (writes pre-scaled hs2)
    hipLaunchKernelGGL(g1mm_k, dim3((N + 15) / 16), dim3(256), 0, stream,
                       hs1, ssrc, rs, dinv, b1, W2, hs2, N, E);
    // layer-2 aggregate
    hipLaunchKernelGGL(gather2_k, dim3((N + 7) / 8), dim3(256), 0, stream,
                       hs2, ssrc, rs, dinv, b2, out, N, E);
}

// Round 3
// 166.434 us; speedup vs baseline: 1.2525x; 1.2525x over previous
//
#include <hip/hip_runtime.h>
#include <hip/hip_fp16.h>

// GCN 2-layer, pull-based CSR gather, fp16 dense intermediates.
// R17 = R15 structure + unweighted gathers WITHOUT the R16 atomic pre-pass:
//  (a) deg_k removed (800k device-scope random atomics was the R16 regression);
//      instead a tiny scale_k after binB multiplies hs1 rows by dinv[row]
//      (dinv comes free from binB's counting sort). gather1 is then a pure
//      sum, same form as gather2: no per-edge dinv[src] gather, no weight shfl.
//  (b) quarter-wave-per-node g1mm gather (16 lanes x f16x8 = 128 dims,
//      4 independent nodes/wave, no serial node loop).
//  (c) eighth-wave-per-node gather2 (8 lanes x f16x8 = 64 dims,
//      8 independent nodes/wave) -> more latency chains per wave.
// Edge preprocessing (bucket counting sort) unchanged. N <= 65536.

typedef _Float16 half_t;
typedef _Float16 half2_t __attribute__((ext_vector_type(2)));
typedef _Float16 f16x4 __attribute__((ext_vector_type(4)));
typedef _Float16 f16x8 __attribute__((ext_vector_type(8)));
typedef float f32x4 __attribute__((ext_vector_type(4)));

#define BKT_CAP 8192   // per-bucket ebuf capacity (expected load 4096, sigma 64)

// inclusive block scan over 256 threads (4 waves); caller provides 4-int LDS
__device__ __forceinline__ int incl_scan256(int v, volatile int* wsum) {
    int t = threadIdx.x, lane = t & 63, w = t >> 6;
#pragma unroll
    for (int off = 1; off < 64; off <<= 1) {
        int u = __shfl_up(v, off);
        if (lane >= off) v += u;
    }
    if (lane == 63) wsum[w] = v;
    __syncthreads();
    int add = 0;
#pragma unroll
    for (int i = 0; i < 3; ++i)
        if (i < w) add += wsum[i];
    return v + add;
}

// ---------------- gemm1: 128x128 tile via f16 MFMA ----------------
// MFMA 16x16x32 layouts (gfx950, HW-verified):
//   A-frag: lane holds A[m=lane&15][k=(lane>>4)*8+j]
//   B-frag: lane holds B[k=(lane>>4)*8+j][n=lane&15]
//   C/D   : col=lane&15, row=(lane>>4)*4+reg

__device__ __forceinline__ void gemm1_mfma(const float* __restrict__ x,
                                           const float* __restrict__ W,
                                           half_t* __restrict__ C, int M, int r0) {
    __shared__ _Float16 Wt[128][136];          // [n][k], rows 272B (b128-aligned)
    __shared__ _Float16 Xs[128][40];           // [m][k-chunk], rows 80B
    const int t = threadIdx.x;

    // stage W^T fp16: coalesced reads along n, b64 writes along k
    {
        const int n = t & 127;
#pragma unroll
        for (int kb = (t >> 7) * 4; kb < 128; kb += 8) {
            f16x4 hv;
            hv[0] = (_Float16)W[(size_t)(kb + 0) * 128 + n];
            hv[1] = (_Float16)W[(size_t)(kb + 1) * 128 + n];
            hv[2] = (_Float16)W[(size_t)(kb + 2) * 128 + n];
            hv[3] = (_Float16)W[(size_t)(kb + 3) * 128 + n];
            *(f16x4*)&Wt[n][kb] = hv;
        }
    }

    const int w = t >> 6, lane = t & 63;
    const int m = lane & 15, q = lane >> 4;

    // Xs staging coords: 16 floats (one row-half-chunk) per thread per kc
    const int sr = t >> 1;               // 0..127 tile row
    const int sk = (t & 1) * 16;         // 0 or 16 within 32-k chunk
    const int srow = (r0 + sr < M) ? (r0 + sr) : (M - 1);

    f32x4 acc[2][8];
#pragma unroll
    for (int rt = 0; rt < 2; ++rt)
#pragma unroll
        for (int ct = 0; ct < 8; ++ct)
#pragma unroll
            for (int r = 0; r < 4; ++r) acc[rt][ct][r] = 0.f;

#pragma unroll
    for (int kc = 0; kc < 4; ++kc) {
        // coalesced global loads issued before the barrier (overlap prev MFMAs)
        const float* xp = &x[(size_t)srow * 128 + kc * 32 + sk];
        float4 v0 = *(const float4*)xp;
        float4 v1 = *(const float4*)(xp + 4);
        float4 v2 = *(const float4*)(xp + 8);
        float4 v3 = *(const float4*)(xp + 12);
        __syncthreads();                 // prev iter's Xs reads done (&& Wt staged)
        f16x8 s0, s1;
        s0[0] = (_Float16)v0.x; s0[1] = (_Float16)v0.y;
        s0[2] = (_Float16)v0.z; s0[3] = (_Float16)v0.w;
        s0[4] = (_Float16)v1.x; s0[5] = (_Float16)v1.y;
        s0[6] = (_Float16)v1.z; s0[7] = (_Float16)v1.w;
        s1[0] = (_Float16)v2.x; s1[1] = (_Float16)v2.y;
        s1[2] = (_Float16)v2.z; s1[3] = (_Float16)v2.w;
        s1[4] = (_Float16)v3.x; s1[5] = (_Float16)v3.y;
        s1[6] = (_Float16)v3.z; s1[7] = (_Float16)v3.w;
        *(f16x8*)&Xs[sr][sk] = s0;
        *(f16x8*)&Xs[sr][sk + 8] = s1;
        __syncthreads();

        const int k0 = q * 8;
        f16x8 a0 = *(const f16x8*)&Xs[(w * 2 + 0) * 16 + m][k0];
        f16x8 a1 = *(const f16x8*)&Xs[(w * 2 + 1) * 16 + m][k0];
        const int kw = kc * 32 + k0;
#pragma unroll
        for (int ct = 0; ct < 8; ++ct) {
            f16x8 b = *(const f16x8*)&Wt[ct * 16 + m][kw];
            acc[0][ct] = __builtin_amdgcn_mfma_f32_16x16x32_f16(a0, b, acc[0][ct], 0, 0, 0);
            acc[1][ct] = __builtin_amdgcn_mfma_f32_16x16x32_f16(a1, b, acc[1][ct], 0, 0, 0);
        }
    }

#pragma unroll
    for (int rt = 0; rt < 2; ++rt)
#pragma unroll
        for (int ct = 0; ct < 8; ++ct)
#pragma unroll
            for (int r = 0; r < 4; ++r) {
                int row = r0 + (w * 2 + rt) * 16 + q * 4 + r;
                if (row < M)
                    C[(size_t)row * 128 + ct * 16 + m] = (half_t)acc[rt][ct][r];
            }
}

// ---------------- k1: gemm1 blocks, then pass-A binning blocks --------------

__launch_bounds__(256)
__global__ void gemm_binA_k(const float* __restrict__ A, const float* __restrict__ W,
                            half_t* __restrict__ C, int M, int Gg1,
                            const int* __restrict__ esrc, const int* __restrict__ edst,
                            int* __restrict__ bucket_cnt, unsigned int* __restrict__ ebuf,
                            int E) {
    int b = blockIdx.x;
    if (b < Gg1) {
        gemm1_mfma(A, W, C, M, b * 128);
        return;
    }
    __shared__ int cntA[256];
    __shared__ int curA[256];
    __shared__ int deltaA[256];
    __shared__ int wsumA[4];

    const int t = threadIdx.x;
    const int base = (b - Gg1) * 4096;
    int ls[16], ld[16];

    cntA[t] = 0;
    __syncthreads();
#pragma unroll
    for (int j = 0; j < 16; ++j) {
        int idx = base + j * 256 + t;
        if (idx < E) {
            ls[j] = esrc[idx];
            ld[j] = edst[idx];
            atomicAdd(&cntA[ld[j] >> 8], 1);
        } else {
            ls[j] = -1;
            ld[j] = 0;
        }
    }
    __syncthreads();

    int c = cntA[t];
    int incl = incl_scan256(c, wsumA);      // contains a __syncthreads
    int excl = incl - c;
    int gbase = atomicAdd(&bucket_cnt[t], c);       // offset within bucket segment
    deltaA[t] = t * BKT_CAP + gbase - excl;         // absolute = seg base + offset
    curA[t] = excl;
    __syncthreads();

#pragma unroll
    for (int j = 0; j < 16; ++j) {
        if (ls[j] >= 0) {
            int bkt = ld[j] >> 8;
            int p = atomicAdd(&curA[bkt], 1);
            ebuf[deltaA[bkt] + p] = ((unsigned int)ls[j] << 8) | ((unsigned int)ld[j] & 255u);
        }
    }
}

// ---------------- k2 (pass B): per-bucket counting sort -> rs/dinv/ssrc -----

__launch_bounds__(256)
__global__ void binB_k(const int* __restrict__ bucket_cnt,
                       const unsigned int* __restrict__ ebuf,
                       unsigned short* __restrict__ ssrc,
                       int* __restrict__ rs, float* __restrict__ dinv,
                       int N, int NB) {
    __shared__ int cnt[256];
    __shared__ int pre[256];
    __shared__ int wsum1[4];
    __shared__ int wsum2[4];

    const int t = threadIdx.x;
    const int b = blockIdx.x;

    int v = (t < NB) ? bucket_cnt[t] : 0;
    int inclb = incl_scan256(v, wsum1);
    pre[t] = inclb;
    __syncthreads();
    const int gb = (b > 0) ? pre[b - 1] : 0;
    const int sz = pre[b] - gb;
    const unsigned int* seg = ebuf + (size_t)b * BKT_CAP;

    cnt[t] = 0;
    __syncthreads();
    for (int i = t; i < sz; i += 256) {
        unsigned int pk = seg[i];
        atomicAdd(&cnt[pk & 255u], 1);
    }
    __syncthreads();

    int c = cnt[t];
    int incl = incl_scan256(c, wsum2);
    int excl = incl - c;
    int node = b * 256 + t;
    if (node < N) {
        rs[node] = gb + excl;
        dinv[node] = rsqrtf(1.0f + (float)c);
    }
    __syncthreads();
    cnt[t] = excl;
    __syncthreads();

    for (int i = t; i < sz; i += 256) {
        unsigned int pk = seg[i];
        int p = atomicAdd(&cnt[pk & 255u], 1);
        ssrc[gb + p] = (unsigned short)(pk >> 8);
    }
}

// ---------------- scale_k: hs1[row] *= dinv[row] (wave per node) ------------

__global__ void scale_k(half_t* __restrict__ hs, const float* __restrict__ dinv, int N) {
    int node = (int)((blockIdx.x * blockDim.x + threadIdx.x) >> 6);
    int lane = threadIdx.x & 63;
    if (node >= N) return;
    float s = dinv[node];
    half2_t* p = (half2_t*)&hs[(size_t)node * 128 + 2 * lane];
    half2_t v = *p;
    v.x = (half_t)((float)v.x * s);
    v.y = (half_t)((float)v.y * s);
    *p = v;
}

// ---------------- g1mm: fused gather1 (quarter-wave/node) + gemm2 -----------
// hs rows pre-scaled by dinv (scale_k), so the aggregate is a pure sum:
// g1_row = relu(dv * (sum_in hs[s] + hs[node]) + b1).
// Per block: 16 nodes; each wave owns 4 concurrent nodes (one per 16-lane
// quarter, f16x8/lane = 128 dims). Rows -> LDS g1s, then M=16 MFMA with
// W2^T; epilogue scales by dinv (pre-scaling hs2 for gather2).

__launch_bounds__(256)
__global__ void g1mm_k(const half_t* __restrict__ hs,
                       const unsigned short* __restrict__ ssrc,
                       const int* __restrict__ rs,
                       const float* __restrict__ dinv,
                       const float* __restrict__ b1,
                       const float* __restrict__ W2,
                       half_t* __restrict__ o, int N, int E) {
    __shared__ _Float16 Wt[64][136];           // [n][k], W2^T fp16
    __shared__ _Float16 g1s[16][136];          // gathered+activated rows
    const int t = threadIdx.x;

    // stage W2^T fp16: coalesced reads along n, b64 writes along k
    {
        const int n = t & 63;
#pragma unroll
        for (int kb = (t >> 6) * 4; kb < 128; kb += 16) {
            f16x4 hv;
            hv[0] = (_Float16)W2[(size_t)(kb + 0) * 64 + n];
            hv[1] = (_Float16)W2[(size_t)(kb + 1) * 64 + n];
            hv[2] = (_Float16)W2[(size_t)(kb + 2) * 64 + n];
            hv[3] = (_Float16)W2[(size_t)(kb + 3) * 64 + n];
            *(f16x4*)&Wt[n][kb] = hv;
        }
    }

    const int w = t >> 6, lane = t & 63;
    const int qd = lane >> 4, l4 = lane & 15;
    const int nb = blockIdx.x * 16;
    const half_t* hp = hs + 8 * l4;            // dims 8*l4 .. 8*l4+7
    const int sl = qd * 16;                    // shfl base for this quarter

    int node = nb + w * 4 + qd;                // this quarter's node
    int vnode = (node < N) ? node : (N - 1);
    int start = rs[vnode];
    int end = (vnode + 1 < N) ? rs[vnode + 1] : E;
    float dv = dinv[vnode];

    f16x8 sv = *(const f16x8*)&hp[(size_t)vnode * 128];   // self (pre-scaled)
    float acc[8];
#pragma unroll
    for (int j = 0; j < 8; ++j) acc[j] = (float)sv[j];

    for (int base = start; base < end; base += 16) {
        int n = end - base;
        if (n > 16) n = 16;
        int gi = (base + l4 < end) ? (base + l4) : base;
        int idx = (int)ssrc[gi];
        int e = 0;
        for (; e + 4 <= n; e += 4) {           // 4 edges in flight per quarter
            int s0 = __shfl(idx, sl + e + 0);
            int s1 = __shfl(idx, sl + e + 1);
            int s2 = __shfl(idx, sl + e + 2);
            int s3 = __shfl(idx, sl + e + 3);
            f16x8 x0 = *(const f16x8*)&hp[(size_t)s0 * 128];
            f16x8 x1 = *(const f16x8*)&hp[(size_t)s1 * 128];
            f16x8 x2 = *(const f16x8*)&hp[(size_t)s2 * 128];
            f16x8 x3 = *(const f16x8*)&hp[(size_t)s3 * 128];
#pragma unroll
            for (int j = 0; j < 8; ++j) acc[j] += (float)x0[j];
#pragma unroll
            for (int j = 0; j < 8; ++j) acc[j] += (float)x1[j];
#pragma unroll
            for (int j = 0; j < 8; ++j) acc[j] += (float)x2[j];
#pragma unroll
            for (int j = 0; j < 8; ++j) acc[j] += (float)x3[j];
        }
        for (; e < n; ++e) {
            int s0 = __shfl(idx, sl + e);
            f16x8 x0 = *(const f16x8*)&hp[(size_t)s0 * 128];
#pragma unroll
            for (int j = 0; j < 8; ++j) acc[j] += (float)x0[j];
        }
    }

    // epilogue: relu(acc*dv + b1) -> LDS row (each quarter owns a full row)
    {
        float4 ba = *(const float4*)&b1[8 * l4];
        float4 bb = *(const float4*)&b1[8 * l4 + 4];
        f16x8 hv;
        hv[0] = (half_t)fmaxf(acc[0] * dv + ba.x, 0.f);
        hv[1] = (half_t)fmaxf(acc[1] * dv + ba.y, 0.f);
        hv[2] = (half_t)fmaxf(acc[2] * dv + ba.z, 0.f);
        hv[3] = (half_t)fmaxf(acc[3] * dv + ba.w, 0.f);
        hv[4] = (half_t)fmaxf(acc[4] * dv + bb.x, 0.f);
        hv[5] = (half_t)fmaxf(acc[5] * dv + bb.y, 0.f);
        hv[6] = (half_t)fmaxf(acc[6] * dv + bb.z, 0.f);
        hv[7] = (half_t)fmaxf(acc[7] * dv + bb.w, 0.f);
        *(f16x8*)&g1s[w * 4 + qd][8 * l4] = hv;
    }
    __syncthreads();

    // M=16 x N=64 x K=128 MFMA; wave w owns output cols w*16..w*16+15
    const int m = lane & 15, q = lane >> 4;
    f32x4 acc2;
#pragma unroll
    for (int r = 0; r < 4; ++r) acc2[r] = 0.f;
#pragma unroll
    for (int kc = 0; kc < 4; ++kc) {
        const int k0 = kc * 32 + q * 8;
        f16x8 a = *(const f16x8*)&g1s[m][k0];
        f16x8 b = *(const f16x8*)&Wt[w * 16 + m][k0];
        acc2 = __builtin_amdgcn_mfma_f32_16x16x32_f16(a, b, acc2, 0, 0, 0);
    }
#pragma unroll
    for (int r = 0; r < 4; ++r) {
        int row = nb + q * 4 + r;
        if (row < N) {
            float s = dinv[row];
            o[(size_t)row * 64 + w * 16 + m] = (half_t)(acc2[r] * s);
        }
    }
}

// ---------------- gather2: 64-dim, eighth-wave per node, fp32 out -----------

__global__ void gather2_k(const half_t* __restrict__ hs,
                          const unsigned short* __restrict__ ssrc,
                          const int* __restrict__ rs,
                          const float* __restrict__ dinv,
                          const float* __restrict__ bias,
                          float* __restrict__ o, int N, int E) {
    int wid = (int)((blockIdx.x * blockDim.x + threadIdx.x) >> 6);
    int lane = threadIdx.x & 63;
    const int sg = lane >> 3, l3 = lane & 7;
    int rnode = wid * 8 + sg;                  // this eighth's node
    int node = (rnode < N) ? rnode : (N - 1);

    int start = rs[node];
    int end = (node + 1 < N) ? rs[node + 1] : E;
    float dv = dinv[node];
    const int sl = sg * 8;

    const half_t* hp = hs + 8 * l3;            // dims 8*l3 .. 8*l3+7
    f16x8 sv = *(const f16x8*)&hp[(size_t)node * 64];
    float acc[8];
#pragma unroll
    for (int j = 0; j < 8; ++j) acc[j] = (float)sv[j];   // self (pre-scaled)

    for (int base = start; base < end; base += 8) {
        int n = end - base;
        if (n > 8) n = 8;
        int gi = (base + l3 < end) ? (base + l3) : base;
        int idx = (int)ssrc[gi];
        int e = 0;
        for (; e + 4 <= n; e += 4) {           // 4 edges in flight per eighth
            int s0 = __shfl(idx, sl + e + 0);
            int s1 = __shfl(idx, sl + e + 1);
            int s2 = __shfl(idx, sl + e + 2);
            int s3 = __shfl(idx, sl + e + 3);
            f16x8 a0 = *(const f16x8*)&hp[(size_t)s0 * 64];
            f16x8 a1 = *(const f16x8*)&hp[(size_t)s1 * 64];
            f16x8 a2 = *(const f16x8*)&hp[(size_t)s2 * 64];
            f16x8 a3 = *(const f16x8*)&hp[(size_t)s3 * 64];
#pragma unroll
            for (int j = 0; j < 8; ++j) acc[j] += (float)a0[j];
#pragma unroll
            for (int j = 0; j < 8; ++j) acc[j] += (float)a1[j];
#pragma unroll
            for (int j = 0; j < 8; ++j) acc[j] += (float)a2[j];
#pragma unroll
            for (int j = 0; j < 8; ++j) acc[j] += (float)a3[j];
        }
        for (; e < n; ++e) {
            int s0 = __shfl(idx, sl + e);
            f16x8 a0 = *(const f16x8*)&hp[(size_t)s0 * 64];
#pragma unroll
            for (int j = 0; j < 8; ++j) acc[j] += (float)a0[j];
        }
    }
    if (rnode < N) {
        float4 b0 = *(const float4*)&bias[8 * l3];
        float4 b1v = *(const float4*)&bias[8 * l3 + 4];
        float4 o0, o1;
        o0.x = acc[0] * dv + b0.x;
        o0.y = acc[1] * dv + b0.y;
        o0.z = acc[2] * dv + b0.z;
        o0.w = acc[3] * dv + b0.w;
        o1.x = acc[4] * dv + b1v.x;
        o1.y = acc[5] * dv + b1v.y;
        o1.z = acc[6] * dv + b1v.z;
        o1.w = acc[7] * dv + b1v.w;
        *(float4*)&o[(size_t)rnode * 64 + 8 * l3] = o0;
        *(float4*)&o[(size_t)rnode * 64 + 8 * l3 + 4] = o1;
    }
}

// ---------------- launcher ----------------

extern "C" void kernel_launch(void* const* d_in, const int* in_sizes, int n_in,
                              void* d_out, int out_size, void* d_ws, size_t ws_size,
                              hipStream_t stream) {
    const float* x  = (const float*)d_in[0];
    const int*   ei = (const int*)d_in[1];
    const float* W1 = (const float*)d_in[2];
    const float* b1 = (const float*)d_in[3];
    const float* W2 = (const float*)d_in[4];
    const float* b2 = (const float*)d_in[5];
    float* out = (float*)d_out;

    const int N = in_sizes[0] / 128;
    const int E = in_sizes[1] / 2;
    const int* esrc = ei;
    const int* edst = ei + E;

    const int NB  = (N + 255) / 256;          // buckets (<=256 requires N<=65536)
    const int Gg1 = (N + 127) / 128;
    const int GA  = (E + 4095) / 4096;

    // workspace layout
    int* bucket_cnt = (int*)d_ws;                             // 256
    unsigned int* ebuf = (unsigned int*)(bucket_cnt + 256);   // NB*BKT_CAP packed edges
    unsigned short* ssrc = (unsigned short*)(ebuf + (size_t)NB * BKT_CAP); // E uint16
    int* rs = (int*)(ssrc + ((E + 1) & ~1));                  // N
    float* dinv = (float*)(rs + N);                           // N
    half_t* hs1 = (half_t*)(dinv + N);                        // N*128 fp16 (scaled in-place)
    half_t* hs2 = hs1 + (size_t)N * 128;                      // N*64 fp16 (pre-scaled)

    hipMemsetAsync(bucket_cnt, 0, 256 * 4, stream);

    // k1: gemm1 (unscaled fp16 h1) ∪ pass-A edge binning
    hipLaunchKernelGGL(gemm_binA_k, dim3(Gg1 + GA), dim3(256), 0, stream,
                       x, W1, hs1, N, Gg1, esrc, edst, bucket_cnt, ebuf, E);
    // k2: per-bucket counting sort -> rs, dinv, ssrc
    hipLaunchKernelGGL(binB_k, dim3(NB), dim3(256), 0, stream,
                       bucket_cnt, ebuf, ssrc, rs, dinv, N, NB);
    // k2.5: pre-scale hs1 rows by dinv (makes gather1 a pure sum)
    hipLaunchKernelGGL(scale_k, dim3((N + 3) / 4), dim3(256), 0, stream,
                       hs1, dinv, N);
    // fused layer-1 aggregate + layer-2 linear (writes pre-scaled hs2)
    hipLaunchKernelGGL(g1mm_k, dim3((N + 15) / 16), dim3(256), 0, stream,
                       hs1, ssrc, rs, dinv, b1, W2, hs2, N, E);
    // layer-2 aggregate
    hipLaunchKernelGGL(gather2_k, dim3((N + 31) / 32), dim3(256), 0, stream,
                       hs2, ssrc, rs, dinv, b2, out, N, E);
}

// Round 4
// 161.785 us; speedup vs baseline: 1.2885x; 1.0287x over previous
//
#include <hip/hip_runtime.h>
#include <hip/hip_fp16.h>

// GCN 2-layer, pull-based CSR gather, fp16 dense intermediates.
// R18 = R17 + source-tiled edge ordering (single change):
//   binB's counting sort key widens from (dst&255) [256 keys] to
//   ((dst&255)<<3)|(src>>13) [2048 keys]. Each node's adjacency list is
//   then grouped by 8192-node source tile (2 MB of hs1 rows -> fits 4 MB
//   per-XCD L2). All quarter-waves process tile-0 edges first, tile-1
//   next, ... giving loose global phase alignment: during phase t the L2s
//   hold mostly tile-t rows, converting random LLC pulls into L2 hits.
//   Gather kernels are UNCHANGED - only the edge order differs.
// Edge preprocessing otherwise unchanged. N <= 65536.

typedef _Float16 half_t;
typedef _Float16 half2_t __attribute__((ext_vector_type(2)));
typedef _Float16 f16x4 __attribute__((ext_vector_type(4)));
typedef _Float16 f16x8 __attribute__((ext_vector_type(8)));
typedef float f32x4 __attribute__((ext_vector_type(4)));

#define BKT_CAP 8192   // per-bucket ebuf capacity (expected load 4096, sigma 64)

// inclusive block scan over 256 threads (4 waves); caller provides 4-int LDS
__device__ __forceinline__ int incl_scan256(int v, volatile int* wsum) {
    int t = threadIdx.x, lane = t & 63, w = t >> 6;
#pragma unroll
    for (int off = 1; off < 64; off <<= 1) {
        int u = __shfl_up(v, off);
        if (lane >= off) v += u;
    }
    if (lane == 63) wsum[w] = v;
    __syncthreads();
    int add = 0;
#pragma unroll
    for (int i = 0; i < 3; ++i)
        if (i < w) add += wsum[i];
    return v + add;
}

// ---------------- gemm1: 128x128 tile via f16 MFMA ----------------
// MFMA 16x16x32 layouts (gfx950, HW-verified):
//   A-frag: lane holds A[m=lane&15][k=(lane>>4)*8+j]
//   B-frag: lane holds B[k=(lane>>4)*8+j][n=lane&15]
//   C/D   : col=lane&15, row=(lane>>4)*4+reg

__device__ __forceinline__ void gemm1_mfma(const float* __restrict__ x,
                                           const float* __restrict__ W,
                                           half_t* __restrict__ C, int M, int r0) {
    __shared__ _Float16 Wt[128][136];          // [n][k], rows 272B (b128-aligned)
    __shared__ _Float16 Xs[128][40];           // [m][k-chunk], rows 80B
    const int t = threadIdx.x;

    // stage W^T fp16: coalesced reads along n, b64 writes along k
    {
        const int n = t & 127;
#pragma unroll
        for (int kb = (t >> 7) * 4; kb < 128; kb += 8) {
            f16x4 hv;
            hv[0] = (_Float16)W[(size_t)(kb + 0) * 128 + n];
            hv[1] = (_Float16)W[(size_t)(kb + 1) * 128 + n];
            hv[2] = (_Float16)W[(size_t)(kb + 2) * 128 + n];
            hv[3] = (_Float16)W[(size_t)(kb + 3) * 128 + n];
            *(f16x4*)&Wt[n][kb] = hv;
        }
    }

    const int w = t >> 6, lane = t & 63;
    const int m = lane & 15, q = lane >> 4;

    // Xs staging coords: 16 floats (one row-half-chunk) per thread per kc
    const int sr = t >> 1;               // 0..127 tile row
    const int sk = (t & 1) * 16;         // 0 or 16 within 32-k chunk
    const int srow = (r0 + sr < M) ? (r0 + sr) : (M - 1);

    f32x4 acc[2][8];
#pragma unroll
    for (int rt = 0; rt < 2; ++rt)
#pragma unroll
        for (int ct = 0; ct < 8; ++ct)
#pragma unroll
            for (int r = 0; r < 4; ++r) acc[rt][ct][r] = 0.f;

#pragma unroll
    for (int kc = 0; kc < 4; ++kc) {
        // coalesced global loads issued before the barrier (overlap prev MFMAs)
        const float* xp = &x[(size_t)srow * 128 + kc * 32 + sk];
        float4 v0 = *(const float4*)xp;
        float4 v1 = *(const float4*)(xp + 4);
        float4 v2 = *(const float4*)(xp + 8);
        float4 v3 = *(const float4*)(xp + 12);
        __syncthreads();                 // prev iter's Xs reads done (&& Wt staged)
        f16x8 s0, s1;
        s0[0] = (_Float16)v0.x; s0[1] = (_Float16)v0.y;
        s0[2] = (_Float16)v0.z; s0[3] = (_Float16)v0.w;
        s0[4] = (_Float16)v1.x; s0[5] = (_Float16)v1.y;
        s0[6] = (_Float16)v1.z; s0[7] = (_Float16)v1.w;
        s1[0] = (_Float16)v2.x; s1[1] = (_Float16)v2.y;
        s1[2] = (_Float16)v2.z; s1[3] = (_Float16)v2.w;
        s1[4] = (_Float16)v3.x; s1[5] = (_Float16)v3.y;
        s1[6] = (_Float16)v3.z; s1[7] = (_Float16)v3.w;
        *(f16x8*)&Xs[sr][sk] = s0;
        *(f16x8*)&Xs[sr][sk + 8] = s1;
        __syncthreads();

        const int k0 = q * 8;
        f16x8 a0 = *(const f16x8*)&Xs[(w * 2 + 0) * 16 + m][k0];
        f16x8 a1 = *(const f16x8*)&Xs[(w * 2 + 1) * 16 + m][k0];
        const int kw = kc * 32 + k0;
#pragma unroll
        for (int ct = 0; ct < 8; ++ct) {
            f16x8 b = *(const f16x8*)&Wt[ct * 16 + m][kw];
            acc[0][ct] = __builtin_amdgcn_mfma_f32_16x16x32_f16(a0, b, acc[0][ct], 0, 0, 0);
            acc[1][ct] = __builtin_amdgcn_mfma_f32_16x16x32_f16(a1, b, acc[1][ct], 0, 0, 0);
        }
    }

#pragma unroll
    for (int rt = 0; rt < 2; ++rt)
#pragma unroll
        for (int ct = 0; ct < 8; ++ct)
#pragma unroll
            for (int r = 0; r < 4; ++r) {
                int row = r0 + (w * 2 + rt) * 16 + q * 4 + r;
                if (row < M)
                    C[(size_t)row * 128 + ct * 16 + m] = (half_t)acc[rt][ct][r];
            }
}

// ---------------- k1: gemm1 blocks, then pass-A binning blocks --------------

__launch_bounds__(256)
__global__ void gemm_binA_k(const float* __restrict__ A, const float* __restrict__ W,
                            half_t* __restrict__ C, int M, int Gg1,
                            const int* __restrict__ esrc, const int* __restrict__ edst,
                            int* __restrict__ bucket_cnt, unsigned int* __restrict__ ebuf,
                            int E) {
    int b = blockIdx.x;
    if (b < Gg1) {
        gemm1_mfma(A, W, C, M, b * 128);
        return;
    }
    __shared__ int cntA[256];
    __shared__ int curA[256];
    __shared__ int deltaA[256];
    __shared__ int wsumA[4];

    const int t = threadIdx.x;
    const int base = (b - Gg1) * 4096;
    int ls[16], ld[16];

    cntA[t] = 0;
    __syncthreads();
#pragma unroll
    for (int j = 0; j < 16; ++j) {
        int idx = base + j * 256 + t;
        if (idx < E) {
            ls[j] = esrc[idx];
            ld[j] = edst[idx];
            atomicAdd(&cntA[ld[j] >> 8], 1);
        } else {
            ls[j] = -1;
            ld[j] = 0;
        }
    }
    __syncthreads();

    int c = cntA[t];
    int incl = incl_scan256(c, wsumA);      // contains a __syncthreads
    int excl = incl - c;
    int gbase = atomicAdd(&bucket_cnt[t], c);       // offset within bucket segment
    deltaA[t] = t * BKT_CAP + gbase - excl;         // absolute = seg base + offset
    curA[t] = excl;
    __syncthreads();

#pragma unroll
    for (int j = 0; j < 16; ++j) {
        if (ls[j] >= 0) {
            int bkt = ld[j] >> 8;
            int p = atomicAdd(&curA[bkt], 1);
            ebuf[deltaA[bkt] + p] = ((unsigned int)ls[j] << 8) | ((unsigned int)ld[j] & 255u);
        }
    }
}

// ---------------- k2 (pass B): per-bucket counting sort -> rs/dinv/ssrc -----
// Sort key = ((dst&255)<<3) | (src>>13): per-node adjacency grouped by
// 8192-node source tile (2 MB hs1 slab -> L2-resident during its phase).

__launch_bounds__(256)
__global__ void binB_k(const int* __restrict__ bucket_cnt,
                       const unsigned int* __restrict__ ebuf,
                       unsigned short* __restrict__ ssrc,
                       int* __restrict__ rs, float* __restrict__ dinv,
                       int N, int NB) {
    __shared__ int cnt[2048];                  // per (dstlow, tile) counters
    __shared__ int pre[256];
    __shared__ int wsum1[4];
    __shared__ int wsum2[4];

    const int t = threadIdx.x;
    const int b = blockIdx.x;

    int v = (t < NB) ? bucket_cnt[t] : 0;
    int inclb = incl_scan256(v, wsum1);
    pre[t] = inclb;
    __syncthreads();
    const int gb = (b > 0) ? pre[b - 1] : 0;
    const int sz = pre[b] - gb;
    const unsigned int* seg = ebuf + (size_t)b * BKT_CAP;

#pragma unroll
    for (int i = 0; i < 8; ++i) cnt[t + i * 256] = 0;
    __syncthreads();
    for (int i = t; i < sz; i += 256) {
        unsigned int pk = seg[i];
        int key = ((pk & 255u) << 3) | ((pk >> 8) >> 13);   // (dstlow, srctile)
        atomicAdd(&cnt[key], 1);
    }
    __syncthreads();

    // thread t owns keys 8t..8t+7 (= node dstlow t, all 8 tiles)
    int c8[8];
    int s = 0;
#pragma unroll
    for (int j = 0; j < 8; ++j) { c8[j] = cnt[t * 8 + j]; s += c8[j]; }
    int incl = incl_scan256(s, wsum2);         // contains a __syncthreads
    int excl = incl - s;
    int node = b * 256 + t;
    if (node < N) {
        rs[node] = gb + excl;
        dinv[node] = rsqrtf(1.0f + (float)s);
    }
    int run = excl;
#pragma unroll
    for (int j = 0; j < 8; ++j) { int cv = c8[j]; cnt[t * 8 + j] = run; run += cv; }
    __syncthreads();

    for (int i = t; i < sz; i += 256) {
        unsigned int pk = seg[i];
        int key = ((pk & 255u) << 3) | ((pk >> 8) >> 13);
        int p = atomicAdd(&cnt[key], 1);
        ssrc[gb + p] = (unsigned short)(pk >> 8);
    }
}

// ---------------- scale_k: hs1[row] *= dinv[row] (wave per node) ------------

__global__ void scale_k(half_t* __restrict__ hs, const float* __restrict__ dinv, int N) {
    int node = (int)((blockIdx.x * blockDim.x + threadIdx.x) >> 6);
    int lane = threadIdx.x & 63;
    if (node >= N) return;
    float s = dinv[node];
    half2_t* p = (half2_t*)&hs[(size_t)node * 128 + 2 * lane];
    half2_t v = *p;
    v.x = (half_t)((float)v.x * s);
    v.y = (half_t)((float)v.y * s);
    *p = v;
}

// ---------------- g1mm: fused gather1 (quarter-wave/node) + gemm2 -----------
// hs rows pre-scaled by dinv (scale_k), so the aggregate is a pure sum:
// g1_row = relu(dv * (sum_in hs[s] + hs[node]) + b1).
// Per block: 16 nodes; each wave owns 4 concurrent nodes (one per 16-lane
// quarter, f16x8/lane = 128 dims). Rows -> LDS g1s, then M=16 MFMA with
// W2^T; epilogue scales by dinv (pre-scaling hs2 for gather2).

__launch_bounds__(256)
__global__ void g1mm_k(const half_t* __restrict__ hs,
                       const unsigned short* __restrict__ ssrc,
                       const int* __restrict__ rs,
                       const float* __restrict__ dinv,
                       const float* __restrict__ b1,
                       const float* __restrict__ W2,
                       half_t* __restrict__ o, int N, int E) {
    __shared__ _Float16 Wt[64][136];           // [n][k], W2^T fp16
    __shared__ _Float16 g1s[16][136];          // gathered+activated rows
    const int t = threadIdx.x;

    // stage W2^T fp16: coalesced reads along n, b64 writes along k
    {
        const int n = t & 63;
#pragma unroll
        for (int kb = (t >> 6) * 4; kb < 128; kb += 16) {
            f16x4 hv;
            hv[0] = (_Float16)W2[(size_t)(kb + 0) * 64 + n];
            hv[1] = (_Float16)W2[(size_t)(kb + 1) * 64 + n];
            hv[2] = (_Float16)W2[(size_t)(kb + 2) * 64 + n];
            hv[3] = (_Float16)W2[(size_t)(kb + 3) * 64 + n];
            *(f16x4*)&Wt[n][kb] = hv;
        }
    }

    const int w = t >> 6, lane = t & 63;
    const int qd = lane >> 4, l4 = lane & 15;
    const int nb = blockIdx.x * 16;
    const half_t* hp = hs + 8 * l4;            // dims 8*l4 .. 8*l4+7
    const int sl = qd * 16;                    // shfl base for this quarter

    int node = nb + w * 4 + qd;                // this quarter's node
    int vnode = (node < N) ? node : (N - 1);
    int start = rs[vnode];
    int end = (vnode + 1 < N) ? rs[vnode + 1] : E;
    float dv = dinv[vnode];

    f16x8 sv = *(const f16x8*)&hp[(size_t)vnode * 128];   // self (pre-scaled)
    float acc[8];
#pragma unroll
    for (int j = 0; j < 8; ++j) acc[j] = (float)sv[j];

    for (int base = start; base < end; base += 16) {
        int n = end - base;
        if (n > 16) n = 16;
        int gi = (base + l4 < end) ? (base + l4) : base;
        int idx = (int)ssrc[gi];
        int e = 0;
        for (; e + 4 <= n; e += 4) {           // 4 edges in flight per quarter
            int s0 = __shfl(idx, sl + e + 0);
            int s1 = __shfl(idx, sl + e + 1);
            int s2 = __shfl(idx, sl + e + 2);
            int s3 = __shfl(idx, sl + e + 3);
            f16x8 x0 = *(const f16x8*)&hp[(size_t)s0 * 128];
            f16x8 x1 = *(const f16x8*)&hp[(size_t)s1 * 128];
            f16x8 x2 = *(const f16x8*)&hp[(size_t)s2 * 128];
            f16x8 x3 = *(const f16x8*)&hp[(size_t)s3 * 128];
#pragma unroll
            for (int j = 0; j < 8; ++j) acc[j] += (float)x0[j];
#pragma unroll
            for (int j = 0; j < 8; ++j) acc[j] += (float)x1[j];
#pragma unroll
            for (int j = 0; j < 8; ++j) acc[j] += (float)x2[j];
#pragma unroll
            for (int j = 0; j < 8; ++j) acc[j] += (float)x3[j];
        }
        for (; e < n; ++e) {
            int s0 = __shfl(idx, sl + e);
            f16x8 x0 = *(const f16x8*)&hp[(size_t)s0 * 128];
#pragma unroll
            for (int j = 0; j < 8; ++j) acc[j] += (float)x0[j];
        }
    }

    // epilogue: relu(acc*dv + b1) -> LDS row (each quarter owns a full row)
    {
        float4 ba = *(const float4*)&b1[8 * l4];
        float4 bb = *(const float4*)&b1[8 * l4 + 4];
        f16x8 hv;
        hv[0] = (half_t)fmaxf(acc[0] * dv + ba.x, 0.f);
        hv[1] = (half_t)fmaxf(acc[1] * dv + ba.y, 0.f);
        hv[2] = (half_t)fmaxf(acc[2] * dv + ba.z, 0.f);
        hv[3] = (half_t)fmaxf(acc[3] * dv + ba.w, 0.f);
        hv[4] = (half_t)fmaxf(acc[4] * dv + bb.x, 0.f);
        hv[5] = (half_t)fmaxf(acc[5] * dv + bb.y, 0.f);
        hv[6] = (half_t)fmaxf(acc[6] * dv + bb.z, 0.f);
        hv[7] = (half_t)fmaxf(acc[7] * dv + bb.w, 0.f);
        *(f16x8*)&g1s[w * 4 + qd][8 * l4] = hv;
    }
    __syncthreads();

    // M=16 x N=64 x K=128 MFMA; wave w owns output cols w*16..w*16+15
    const int m = lane & 15, q = lane >> 4;
    f32x4 acc2;
#pragma unroll
    for (int r = 0; r < 4; ++r) acc2[r] = 0.f;
#pragma unroll
    for (int kc = 0; kc < 4; ++kc) {
        const int k0 = kc * 32 + q * 8;
        f16x8 a = *(const f16x8*)&g1s[m][k0];
        f16x8 b = *(const f16x8*)&Wt[w * 16 + m][k0];
        acc2 = __builtin_amdgcn_mfma_f32_16x16x32_f16(a, b, acc2, 0, 0, 0);
    }
#pragma unroll
    for (int r = 0; r < 4; ++r) {
        int row = nb + q * 4 + r;
        if (row < N) {
            float s = dinv[row];
            o[(size_t)row * 64 + w * 16 + m] = (half_t)(acc2[r] * s);
        }
    }
}

// ---------------- gather2: 64-dim, eighth-wave per node, fp32 out -----------

__global__ void gather2_k(const half_t* __restrict__ hs,
                          const unsigned short* __restrict__ ssrc,
                          const int* __restrict__ rs,
                          const float* __restrict__ dinv,
                          const float* __restrict__ bias,
                          float* __restrict__ o, int N, int E) {
    int wid = (int)((blockIdx.x * blockDim.x + threadIdx.x) >> 6);
    int lane = threadIdx.x & 63;
    const int sg = lane >> 3, l3 = lane & 7;
    int rnode = wid * 8 + sg;                  // this eighth's node
    int node = (rnode < N) ? rnode : (N - 1);

    int start = rs[node];
    int end = (node + 1 < N) ? rs[node + 1] : E;
    float dv = dinv[node];
    const int sl = sg * 8;

    const half_t* hp = hs + 8 * l3;            // dims 8*l3 .. 8*l3+7
    f16x8 sv = *(const f16x8*)&hp[(size_t)node * 64];
    float acc[8];
#pragma unroll
    for (int j = 0; j < 8; ++j) acc[j] = (float)sv[j];   // self (pre-scaled)

    for (int base = start; base < end; base += 8) {
        int n = end - base;
        if (n > 8) n = 8;
        int gi = (base + l3 < end) ? (base + l3) : base;
        int idx = (int)ssrc[gi];
        int e = 0;
        for (; e + 4 <= n; e += 4) {           // 4 edges in flight per eighth
            int s0 = __shfl(idx, sl + e + 0);
            int s1 = __shfl(idx, sl + e + 1);
            int s2 = __shfl(idx, sl + e + 2);
            int s3 = __shfl(idx, sl + e + 3);
            f16x8 a0 = *(const f16x8*)&hp[(size_t)s0 * 64];
            f16x8 a1 = *(const f16x8*)&hp[(size_t)s1 * 64];
            f16x8 a2 = *(const f16x8*)&hp[(size_t)s2 * 64];
            f16x8 a3 = *(const f16x8*)&hp[(size_t)s3 * 64];
#pragma unroll
            for (int j = 0; j < 8; ++j) acc[j] += (float)a0[j];
#pragma unroll
            for (int j = 0; j < 8; ++j) acc[j] += (float)a1[j];
#pragma unroll
            for (int j = 0; j < 8; ++j) acc[j] += (float)a2[j];
#pragma unroll
            for (int j = 0; j < 8; ++j) acc[j] += (float)a3[j];
        }
        for (; e < n; ++e) {
            int s0 = __shfl(idx, sl + e);
            f16x8 a0 = *(const f16x8*)&hp[(size_t)s0 * 64];
#pragma unroll
            for (int j = 0; j < 8; ++j) acc[j] += (float)a0[j];
        }
    }
    if (rnode < N) {
        float4 b0 = *(const float4*)&bias[8 * l3];
        float4 b1v = *(const float4*)&bias[8 * l3 + 4];
        float4 o0, o1;
        o0.x = acc[0] * dv + b0.x;
        o0.y = acc[1] * dv + b0.y;
        o0.z = acc[2] * dv + b0.z;
        o0.w = acc[3] * dv + b0.w;
        o1.x = acc[4] * dv + b1v.x;
        o1.y = acc[5] * dv + b1v.y;
        o1.z = acc[6] * dv + b1v.z;
        o1.w = acc[7] * dv + b1v.w;
        *(float4*)&o[(size_t)rnode * 64 + 8 * l3] = o0;
        *(float4*)&o[(size_t)rnode * 64 + 8 * l3 + 4] = o1;
    }
}

// ---------------- launcher ----------------

extern "C" void kernel_launch(void* const* d_in, const int* in_sizes, int n_in,
                              void* d_out, int out_size, void* d_ws, size_t ws_size,
                              hipStream_t stream) {
    const float* x  = (const float*)d_in[0];
    const int*   ei = (const int*)d_in[1];
    const float* W1 = (const float*)d_in[2];
    const float* b1 = (const float*)d_in[3];
    const float* W2 = (const float*)d_in[4];
    const float* b2 = (const float*)d_in[5];
    float* out = (float*)d_out;

    const int N = in_sizes[0] / 128;
    const int E = in_sizes[1] / 2;
    const int* esrc = ei;
    const int* edst = ei + E;

    const int NB  = (N + 255) / 256;          // buckets (<=256 requires N<=65536)
    const int Gg1 = (N + 127) / 128;
    const int GA  = (E + 4095) / 4096;

    // workspace layout
    int* bucket_cnt = (int*)d_ws;                             // 256
    unsigned int* ebuf = (unsigned int*)(bucket_cnt + 256);   // NB*BKT_CAP packed edges
    unsigned short* ssrc = (unsigned short*)(ebuf + (size_t)NB * BKT_CAP); // E uint16
    int* rs = (int*)(ssrc + ((E + 1) & ~1));                  // N
    float* dinv = (float*)(rs + N);                           // N
    half_t* hs1 = (half_t*)(dinv + N);                        // N*128 fp16 (scaled in-place)
    half_t* hs2 = hs1 + (size_t)N * 128;                      // N*64 fp16 (pre-scaled)

    hipMemsetAsync(bucket_cnt, 0, 256 * 4, stream);

    // k1: gemm1 (unscaled fp16 h1) ∪ pass-A edge binning
    hipLaunchKernelGGL(gemm_binA_k, dim3(Gg1 + GA), dim3(256), 0, stream,
                       x, W1, hs1, N, Gg1, esrc, edst, bucket_cnt, ebuf, E);
    // k2: per-bucket counting sort (dst, src-tile) -> rs, dinv, ssrc
    hipLaunchKernelGGL(binB_k, dim3(NB), dim3(256), 0, stream,
                       bucket_cnt, ebuf, ssrc, rs, dinv, N, NB);
    // k2.5: pre-scale hs1 rows by dinv (makes gather1 a pure sum)
    hipLaunchKernelGGL(scale_k, dim3((N + 3) / 4), dim3(256), 0, stream,
                       hs1, dinv, N);
    // fused layer-1 aggregate + layer-2 linear (writes pre-scaled hs2)
    hipLaunchKernelGGL(g1mm_k, dim3((N + 15) / 16), dim3(256), 0, stream,
                       hs1, ssrc, rs, dinv, b1, W2, hs2, N, E);
    // layer-2 aggregate
    hipLaunchKernelGGL(gather2_k, dim3((N + 31) / 32), dim3(256), 0, stream,
                       hs2, ssrc, rs, dinv, b2, out, N, E);
}